// Round 14
// baseline (270.971 us; speedup 1.0000x reference)
//
#include <hip/hip_runtime.h>
#include <math.h>
#include <stdint.h>

// Problem constants
#define N_B 4
#define N_H 16
#define L_Q 2048
#define L_K 2048
#define E_D 1024
#define DH  64
#define QB  128          // main kernel q-rows per block (8 waves x 16 rows)
#define KB  64
#define NT  512
#define NQT (L_Q / QB)   // 16
#define NKT (L_K / KB)   // 32
#define LDP  72          // padded stride (f16) for Ps
#define TILE 4096        // one 64x64 f16 tile in LDS (8 KB)

typedef _Float16 f16x2 __attribute__((ext_vector_type(2)));
typedef _Float16 f16x4 __attribute__((ext_vector_type(4)));
typedef _Float16 f16x8 __attribute__((ext_vector_type(8)));
typedef float    f32x4 __attribute__((ext_vector_type(4)));

__device__ __forceinline__ f16x4 pk4(float a, float b, float c, float d) {
    f16x2 lo = __builtin_bit_cast(f16x2, __builtin_amdgcn_cvt_pkrtz(a, b));
    f16x2 hi = __builtin_bit_cast(f16x2, __builtin_amdgcn_cvt_pkrtz(c, d));
    f16x4 r; r[0] = lo[0]; r[1] = lo[1]; r[2] = hi[0]; r[3] = hi[1];
    return r;
}

__device__ __forceinline__ f16x8 pk8(float4 a, float4 b) {
    f16x4 lo = pk4(a.x, a.y, a.z, a.w);
    f16x4 hi = pk4(b.x, b.y, b.z, b.w);
    return __builtin_shufflevector(lo, hi, 0, 1, 2, 3, 4, 5, 6, 7);
}

__device__ __forceinline__ void gload16(const _Float16* g, _Float16* l) {
    __builtin_amdgcn_global_load_lds(
        (const __attribute__((address_space(1))) void*)g,
        (__attribute__((address_space(3))) void*)l, 16, 0, 0);
}

// ======================= fused prep kernel (K convert + V transpose) =========
__global__ __launch_bounds__(256)
void cvt_kv(const float* __restrict__ K, const float* __restrict__ V,
            _Float16* __restrict__ Kh, _Float16* __restrict__ Vt)
{
    __shared__ _Float16 T[64][72];
    const int b = blockIdx.x;
    const int t = threadIdx.x;
    if (b < 4096) {                       // ---- K: f32 -> f16 copy-convert ----
        size_t i = ((size_t)b * 256 + t) * 8;
        float4 c = *(const float4*)(K + i);
        float4 d = *(const float4*)(K + i + 4);
        *(f16x4*)(Kh + i)     = pk4(c.x, c.y, c.z, c.w);
        *(f16x4*)(Kh + i + 4) = pk4(d.x, d.y, d.z, d.w);
        return;
    }
    // ---- V: f32 -> f16 transpose per (n,h) 64x64 tile ----
    const int bid = b - 4096;
    const int st  = bid & 31;
    const int nh  = bid >> 5;
    const int n   = nh >> 4;
    const int h   = nh & 15;
    const float* Vb = V + ((size_t)(n * L_K + st * 64)) * E_D + h * DH;
    #pragma unroll
    for (int i = 0; i < 4; ++i) {
        int lin = t + i * 256;
        int s = lin >> 4, d = (lin & 15) * 4;
        float4 v = *(const float4*)(Vb + (size_t)s * E_D + d);
        T[d + 0][s] = (_Float16)v.x; T[d + 1][s] = (_Float16)v.y;
        T[d + 2][s] = (_Float16)v.z; T[d + 3][s] = (_Float16)v.w;
    }
    __syncthreads();
    _Float16* Ob = Vt + ((size_t)nh * DH) * L_K + st * 64;
    #pragma unroll
    for (int j = 0; j < 2; ++j) {
        int lin = t + j * 256;
        int d = lin >> 3, sc = (lin & 7) * 8;
        *(f16x8*)(Ob + (size_t)d * L_K + sc) = *(const f16x8*)&T[d][sc];
    }
}

// ======================= main kernel =======================
// Pass A: 3-slot pair-ring, counted vmcnt(2).  Pass B: counted vmcnt(4),
// coalesced nt stores.  qt order interleaves long/short tiles so early
// cohorts contain store-heavy (zero-fill) blocks -> write pipe busy from t=0.
__global__ __launch_bounds__(NT)
void mha_main(const float* __restrict__ Qg, const _Float16* __restrict__ Kh,
              const _Float16* __restrict__ Vth, const int* __restrict__ causp,
              float* __restrict__ Yg, float* __restrict__ Wg)
{
    // flat LDS arena: pass A = 6 tiles (3 pair-slots); pass B = 4 tiles + Ps
    __shared__ __attribute__((aligned(16))) _Float16 SM[25600];   // 51.2 KB
    __shared__ float linv[QB];

    const int tid  = threadIdx.x;
    const int lane = tid & 63;
    const int wid  = tid >> 6;            // 0..7, band of 16 q-rows
    const int bid0 = blockIdx.x;
    const int bid  = ((bid0 & 7) << 7) + (bid0 >> 3);   // XCD swizzle (1024 % 8 == 0)
    const int jj   = bid & (NQT - 1);
    // interleave long/short: 15,0,14,1,13,2,... keeps store-heavy blocks in
    // every dispatch cohort (fills early-epoch write-pipe idle).
    const int qt   = (jj & 1) ? (jj >> 1) : (NQT - 1 - (jj >> 1));
    const int nh   = bid >> 4;
    const int q0   = qt * QB;
    const int n    = nh >> 4;
    const int h    = nh & 15;
    const bool causal = (*causp) != 0;
    const float scale = 0.125f;

    const int lrow = lane & 15;           // q within 16 (C/D col, B-frag col)
    const int g    = lane >> 4;
    const int rb   = wid * 16;            // wave's q-band within block
    const int rsub = g * 4;
    const int kt_end = causal ? (2 * qt + 2) : NKT;   // always even

    float*  Ybase = Yg + ((size_t)(n * L_Q + q0)) * E_D + h * DH;
    float*  Wbase = Wg + ((size_t)nh * L_Q + q0) * L_K;

    // ---- staging source addresses (inverse-swizzled per-lane; rule #21) ----
    const int srow = wid * 8 + (lane >> 3);               // tile row (64 rows, 8 waves)
    const int scol = (((lane & 7) ^ ((lane >> 3) & 7)) << 3);
    const _Float16* Ksrc0 = Kh  + ((size_t)(n * L_K) + srow) * E_D + h * DH + scol;
    const _Float16* Vsrc0 = Vth + ((size_t)nh * DH + srow) * L_K + scol;

    // ---- swizzled fragment read offsets ----
    const int swz = (lrow & 7) << 4;                      // bytes
    const int cb0 = ((g * 16) ^ swz) >> 1;                // elements
    const int cb1 = ((64 + g * 16) ^ swz) >> 1;

    // ---- Q fragments: f32 global -> f16 regs (same pk4 numerics as prep) ----
    const float* Qrowf = Qg + ((size_t)(n * L_Q + q0 + rb + lrow)) * E_D + h * DH;
    const f16x8 qf0 = pk8(*(const float4*)(Qrowf + g * 8),
                          *(const float4*)(Qrowf + g * 8 + 4));
    const f16x8 qf1 = pk8(*(const float4*)(Qrowf + 32 + g * 8),
                          *(const float4*)(Qrowf + 32 + g * 8 + 4));

    #define KSL(b)    (SM + (b) * TILE)
    #define VSL(b)    (SM + (2 + (b)) * TILE)
    #define PS_ROW(r) (SM + 4 * TILE + (size_t)(r) * LDP)
    #define FRAG(buf, tc, half) (*(const f16x8*)&(buf)[(size_t)((tc) * 16 + lrow) * 64 + ((half) ? cb1 : cb0)])

    // ============ PASS A: row sums (m == 0), 3-slot pair-ring ============
    float l_part = 0.0f;
    {
        const int np = kt_end >> 1;
        gload16(Ksrc0 + (size_t)0 * KB * E_D, SM + 0 * 8192 + wid * 512);
        gload16(Ksrc0 + (size_t)1 * KB * E_D, SM + 0 * 8192 + TILE + wid * 512);
        if (np > 1) {
            gload16(Ksrc0 + (size_t)2 * KB * E_D, SM + 1 * 8192 + wid * 512);
            gload16(Ksrc0 + (size_t)3 * KB * E_D, SM + 1 * 8192 + TILE + wid * 512);
        }
        int slot = 0;
        for (int p = 0; p < np; ++p) {
            __builtin_amdgcn_sched_barrier(0);
            if (p + 1 < np) {
                asm volatile("s_waitcnt vmcnt(2) lgkmcnt(0)" ::: "memory");
            } else {
                asm volatile("s_waitcnt vmcnt(0) lgkmcnt(0)" ::: "memory");
            }
            __builtin_amdgcn_s_barrier();
            __builtin_amdgcn_sched_barrier(0);
            if (p + 2 < np) {
                int ns = slot + 2; if (ns >= 3) ns -= 3;
                gload16(Ksrc0 + (size_t)(2 * p + 4) * KB * E_D, SM + ns * 8192 + wid * 512);
                gload16(Ksrc0 + (size_t)(2 * p + 5) * KB * E_D, SM + ns * 8192 + TILE + wid * 512);
            }
            __builtin_amdgcn_sched_barrier(0);
            const _Float16* base = SM + slot * 8192;
            #pragma unroll
            for (int half = 0; half < 2; ++half) {
                const int kt = 2 * p + half;
                const _Float16* Kc = base + half * TILE;
                f32x4 acc[4] = {};
                #pragma unroll
                for (int tc = 0; tc < 4; ++tc) {
                    acc[tc] = __builtin_amdgcn_mfma_f32_16x16x32_f16(FRAG(Kc, tc, 0), qf0, acc[tc], 0, 0, 0);
                    acc[tc] = __builtin_amdgcn_mfma_f32_16x16x32_f16(FRAG(Kc, tc, 1), qf1, acc[tc], 0, 0, 0);
                }
                const bool dm = causal && (kt >= 2 * qt);
                const int krel = (kt - 2 * qt) * 64;
                #pragma unroll
                for (int tc = 0; tc < 4; ++tc) {
                    #pragma unroll
                    for (int i = 0; i < 4; ++i) {
                        float v = acc[tc][i] * scale;
                        bool ok = !dm || (krel + tc * 16 + rsub + i <= rb + lrow);
                        l_part += ok ? __expf(v) : 0.0f;
                    }
                }
            }
            slot = slot + 1; if (slot >= 3) slot = 0;
        }
        __syncthreads();   // all ring reads done before pass-B staging / Ps writes
    }
    l_part += __shfl_xor(l_part, 16);
    l_part += __shfl_xor(l_part, 32);
    const float inv_l = 1.0f / l_part;
    linv[rb + lrow] = inv_l;   // 4 lanes write same value: benign

    // ================= PASS B: W write + O^T = V^T P^T =================
    f32x4 o[4] = {};
    gload16(Ksrc0, KSL(0) + wid * 512);
    gload16(Vsrc0, VSL(0) + wid * 512);
    __syncthreads();           // buffers full; also publishes linv

    float winv[4];
    #pragma unroll
    for (int j = 0; j < 4; ++j) winv[j] = linv[rb + (lane >> 4) + 4 * j];

    for (int kt = 0; kt < kt_end; ++kt) {
        const int cur = kt & 1;
        if (kt + 1 < kt_end) {
            gload16(Ksrc0 + (size_t)(kt + 1) * KB * E_D, KSL(cur ^ 1) + wid * 512);
            gload16(Vsrc0 + (size_t)(kt + 1) * KB,       VSL(cur ^ 1) + wid * 512);
        }

        f32x4 acc[4] = {};
        #pragma unroll
        for (int tc = 0; tc < 4; ++tc) {
            acc[tc] = __builtin_amdgcn_mfma_f32_16x16x32_f16(FRAG(KSL(cur), tc, 0), qf0, acc[tc], 0, 0, 0);
            acc[tc] = __builtin_amdgcn_mfma_f32_16x16x32_f16(FRAG(KSL(cur), tc, 1), qf1, acc[tc], 0, 0, 0);
        }

        const bool dm = causal && (kt >= 2 * qt);
        const int krel = (kt - 2 * qt) * 64;
        #pragma unroll
        for (int tc = 0; tc < 4; ++tc) {
            float v, p0, p1, p2, p3;
            v = acc[tc][0] * scale;
            p0 = (!dm || (krel + tc * 16 + rsub + 0 <= rb + lrow)) ? __expf(v) : 0.0f;
            v = acc[tc][1] * scale;
            p1 = (!dm || (krel + tc * 16 + rsub + 1 <= rb + lrow)) ? __expf(v) : 0.0f;
            v = acc[tc][2] * scale;
            p2 = (!dm || (krel + tc * 16 + rsub + 2 <= rb + lrow)) ? __expf(v) : 0.0f;
            v = acc[tc][3] * scale;
            p3 = (!dm || (krel + tc * 16 + rsub + 3 <= rb + lrow)) ? __expf(v) : 0.0f;
            *(f16x4*)(PS_ROW(rb + lrow) + tc * 16 + rsub) = pk4(p0, p1, p2, p3);
        }
        // Ps rows rb..rb+15 written & read by this wave only: lgkmcnt orders it.

        f16x8 pf0 = *(const f16x8*)(PS_ROW(rb + lrow) + g * 8);
        f16x8 pf1 = *(const f16x8*)(PS_ROW(rb + lrow) + 32 + g * 8);
        #pragma unroll
        for (int tc = 0; tc < 4; ++tc) {
            o[tc] = __builtin_amdgcn_mfma_f32_16x16x32_f16(FRAG(VSL(cur), tc, 0), pf0, o[tc], 0, 0, 0);
            o[tc] = __builtin_amdgcn_mfma_f32_16x16x32_f16(FRAG(VSL(cur), tc, 1), pf1, o[tc], 0, 0, 0);
        }

        // ---- coalesced W store: lanes 0-15 cover one full row (256 B) ----
        {
            float* Wt = Wbase + (size_t)kt * KB;
            const int c0 = (lane & 15) * 4;
            #pragma unroll
            for (int j = 0; j < 4; ++j) {
                const int rl = rb + (lane >> 4) + 4 * j;   // this wave's rows
                f16x4 pv = *(const f16x4*)(PS_ROW(rl) + c0);
                const float s = winv[j];
                f32x4 wv = { (float)pv[0] * s, (float)pv[1] * s,
                             (float)pv[2] * s, (float)pv[3] * s };
                __builtin_nontemporal_store(wv, (f32x4*)(Wt + (size_t)rl * L_K + c0));
            }
        }

        // counted-vmcnt barrier (T4): drain the 2 prefetch loads (and older
        // stores); this iteration's 4 W-stores stay in flight.
        __builtin_amdgcn_sched_barrier(0);
        asm volatile("s_waitcnt vmcnt(4) lgkmcnt(0)" ::: "memory");
        __builtin_amdgcn_s_barrier();
        __builtin_amdgcn_sched_barrier(0);
    }

    // ---- Y write ----
    #pragma unroll
    for (int tc = 0; tc < 4; ++tc) {
        f32x4 yv = { o[tc][0] * inv_l, o[tc][1] * inv_l,
                     o[tc][2] * inv_l, o[tc][3] * inv_l };
        __builtin_nontemporal_store(yv, (f32x4*)(Ybase + (size_t)(rb + lrow) * E_D + tc * 16 + rsub));
    }

    // ---- zero-fill masked upper columns ----
    if (causal && kt_end < NKT) {
        const int c0 = kt_end * KB;
        const int rem4 = (L_K - c0) >> 2;
        const f32x4 z = { 0.f, 0.f, 0.f, 0.f };
        for (int r = 0; r < QB; ++r) {
            float* row = Wbase + (size_t)r * L_K + c0;
            for (int c4 = tid; c4 < rem4; c4 += NT) {
                __builtin_nontemporal_store(z, (f32x4*)(row + c4 * 4));
            }
        }
    }
    #undef KSL
    #undef VSL
    #undef PS_ROW
    #undef FRAG
}

// ======================= fallback (round-3 proven kernel) =======================
__global__ __launch_bounds__(256)
void mha_fwd_fallback(const float* __restrict__ Qg, const float* __restrict__ Kg,
                      const float* __restrict__ Vg, const int* __restrict__ causp,
                      float* __restrict__ Yg, float* __restrict__ Wg)
{
    __shared__ __attribute__((aligned(16))) _Float16 Qs[64][LDP];
    __shared__ __attribute__((aligned(16))) _Float16 Ks[64][LDP];
    __shared__ __attribute__((aligned(16))) _Float16 Psf[64][LDP];
    __shared__ __attribute__((aligned(16))) _Float16 Vt[DH][68];

    const int tid  = threadIdx.x;
    const int lane = tid & 63;
    const int wid  = tid >> 6;
    const int bid  = blockIdx.x;
    const int qt   = bid & 31;
    const int nh   = bid >> 5;
    const int q0   = qt * 64;
    const int n    = nh >> 4;
    const int h    = nh & 15;
    const bool causal = (*causp) != 0;
    const float scale = 0.125f;

    const float* Qbase = Qg + ((size_t)(n * L_Q + q0)) * E_D + h * DH;
    const float* Kbase = Kg + ((size_t)n * L_K) * E_D + h * DH;
    const float* Vbase = Vg + ((size_t)n * L_K) * E_D + h * DH;
    float*       Ybase = Yg + ((size_t)(n * L_Q + q0)) * E_D + h * DH;
    float*       Wbase = Wg + ((size_t)nh * L_Q + q0) * L_K;

    const int lrow = lane & 15;
    const int lk   = (lane >> 4) * 8;
    const int rb   = wid * 16;
    const int rsub = (lane >> 4) * 4;
    const int kt_end = causal ? (qt + 1) : NKT;

    #pragma unroll
    for (int i = 0; i < 4; ++i) {
        int lin = tid + i * 256;
        int r = lin >> 4;
        int c = (lin & 15) * 4;
        float4 qv = *(const float4*)(Qbase + (size_t)r * E_D + c);
        *(f16x4*)&Qs[r][c] = pk4(qv.x, qv.y, qv.z, qv.w);
    }
    __syncthreads();
    const f16x8 qf0 = *(const f16x8*)&Qs[rb + lrow][lk];
    const f16x8 qf1 = *(const f16x8*)&Qs[rb + lrow][32 + lk];

    float l_part = 0.0f;
    for (int kt = 0; kt < kt_end; ++kt) {
        const float* Kt = Kbase + (size_t)kt * KB * E_D;
        __syncthreads();
        #pragma unroll
        for (int i = 0; i < 4; ++i) {
            int lin = tid + i * 256;
            int r = lin >> 4;
            int c = (lin & 15) * 4;
            float4 kv = *(const float4*)(Kt + (size_t)r * E_D + c);
            *(f16x4*)&Ks[r][c] = pk4(kv.x, kv.y, kv.z, kv.w);
        }
        __syncthreads();
        f32x4 acc[4] = {};
        #pragma unroll
        for (int tc = 0; tc < 4; ++tc) {
            f16x8 a0 = *(const f16x8*)&Ks[tc * 16 + lrow][lk];
            f16x8 a1 = *(const f16x8*)&Ks[tc * 16 + lrow][32 + lk];
            acc[tc] = __builtin_amdgcn_mfma_f32_16x16x32_f16(a0, qf0, acc[tc], 0, 0, 0);
            acc[tc] = __builtin_amdgcn_mfma_f32_16x16x32_f16(a1, qf1, acc[tc], 0, 0, 0);
        }
        const bool dm = causal && (kt == qt);
        #pragma unroll
        for (int tc = 0; tc < 4; ++tc) {
            #pragma unroll
            for (int i = 0; i < 4; ++i) {
                float v = acc[tc][i] * scale;
                bool ok = !dm || (tc * 16 + rsub + i <= rb + lrow);
                l_part += ok ? __expf(v) : 0.0f;
            }
        }
    }
    l_part += __shfl_xor(l_part, 16);
    l_part += __shfl_xor(l_part, 32);
    const float inv_l = 1.0f / l_part;

    f32x4 o[4] = {};
    for (int kt = 0; kt < kt_end; ++kt) {
        const float* Kt  = Kbase + (size_t)kt * KB * E_D;
        const float* Vtg = Vbase + (size_t)kt * KB * E_D;
        __syncthreads();
        #pragma unroll
        for (int i = 0; i < 4; ++i) {
            int lin = tid + i * 256;
            int r = lin >> 4;
            int c = (lin & 15) * 4;
            float4 kv = *(const float4*)(Kt + (size_t)r * E_D + c);
            *(f16x4*)&Ks[r][c] = pk4(kv.x, kv.y, kv.z, kv.w);
            int d   = lin & 63;
            int kk0 = (lin >> 6) * 4;
            float v0 = Vtg[(size_t)(kk0 + 0) * E_D + d];
            float v1 = Vtg[(size_t)(kk0 + 1) * E_D + d];
            float v2 = Vtg[(size_t)(kk0 + 2) * E_D + d];
            float v3 = Vtg[(size_t)(kk0 + 3) * E_D + d];
            *(f16x4*)&Vt[d][kk0] = pk4(v0, v1, v2, v3);
        }
        __syncthreads();
        f32x4 acc[4] = {};
        #pragma unroll
        for (int tc = 0; tc < 4; ++tc) {
            f16x8 a0 = *(const f16x8*)&Ks[tc * 16 + lrow][lk];
            f16x8 a1 = *(const f16x8*)&Ks[tc * 16 + lrow][32 + lk];
            acc[tc] = __builtin_amdgcn_mfma_f32_16x16x32_f16(a0, qf0, acc[tc], 0, 0, 0);
            acc[tc] = __builtin_amdgcn_mfma_f32_16x16x32_f16(a1, qf1, acc[tc], 0, 0, 0);
        }
        const bool dm = causal && (kt == qt);
        float* Wrow = Wbase + (size_t)(rb + lrow) * L_K + kt * KB;
        #pragma unroll
        for (int tc = 0; tc < 4; ++tc) {
            float v, p0, p1, p2, p3;
            v = acc[tc][0] * scale;
            p0 = (!dm || (tc * 16 + rsub + 0 <= rb + lrow)) ? __expf(v) : 0.0f;
            v = acc[tc][1] * scale;
            p1 = (!dm || (tc * 16 + rsub + 1 <= rb + lrow)) ? __expf(v) : 0.0f;
            v = acc[tc][2] * scale;
            p2 = (!dm || (tc * 16 + rsub + 2 <= rb + lrow)) ? __expf(v) : 0.0f;
            v = acc[tc][3] * scale;
            p3 = (!dm || (tc * 16 + rsub + 3 <= rb + lrow)) ? __expf(v) : 0.0f;
            float4 wv = make_float4(p0 * inv_l, p1 * inv_l, p2 * inv_l, p3 * inv_l);
            *(float4*)(Wrow + tc * 16 + rsub) = wv;
            *(f16x4*)&Psf[rb + lrow][tc * 16 + rsub] = pk4(p0, p1, p2, p3);
        }
        f16x8 pf0 = *(const f16x8*)&Psf[rb + lrow][lk];
        f16x8 pf1 = *(const f16x8*)&Psf[rb + lrow][32 + lk];
        #pragma unroll
        for (int tc = 0; tc < 4; ++tc) {
            f16x4 t0 = *(const f16x4*)&Vt[tc * 16 + lrow][lk];
            f16x4 t1 = *(const f16x4*)&Vt[tc * 16 + lrow][lk + 4];
            f16x8 a0 = __builtin_shufflevector(t0, t1, 0, 1, 2, 3, 4, 5, 6, 7);
            f16x4 t2 = *(const f16x4*)&Vt[tc * 16 + lrow][32 + lk];
            f16x4 t3 = *(const f16x4*)&Vt[tc * 16 + lrow][32 + lk + 4];
            f16x8 a1 = __builtin_shufflevector(t2, t3, 0, 1, 2, 3, 4, 5, 6, 7);
            o[tc] = __builtin_amdgcn_mfma_f32_16x16x32_f16(a0, pf0, o[tc], 0, 0, 0);
            o[tc] = __builtin_amdgcn_mfma_f32_16x16x32_f16(a1, pf1, o[tc], 0, 0, 0);
        }
    }
    #pragma unroll
    for (int tc = 0; tc < 4; ++tc) {
        float4 yv = make_float4(o[tc][0] * inv_l, o[tc][1] * inv_l,
                                o[tc][2] * inv_l, o[tc][3] * inv_l);
        *(float4*)(Ybase + (size_t)(rb + lrow) * E_D + tc * 16 + rsub) = yv;
    }
    if (causal && kt_end < NKT) {
        const int c0 = kt_end * KB;
        const int rem4 = (L_K - c0) >> 2;
        const float4 z = make_float4(0.f, 0.f, 0.f, 0.f);
        for (int r = 0; r < 64; ++r) {
            float* row = Wbase + (size_t)r * L_K + c0;
            for (int c4 = tid; c4 < rem4; c4 += 256) {
                *(float4*)(row + c4 * 4) = z;
            }
        }
    }
}

extern "C" void kernel_launch(void* const* d_in, const int* in_sizes, int n_in,
                              void* d_out, int out_size, void* d_ws, size_t ws_size,
                              hipStream_t stream) {
    const float* Q  = (const float*)d_in[0];
    const float* K  = (const float*)d_in[1];
    const float* V  = (const float*)d_in[2];
    const int* caus = (const int*)d_in[3];
    float* Y = (float*)d_out;
    float* W = (float*)d_out + (size_t)N_B * L_Q * E_D;

    const size_t elems = (size_t)N_B * L_Q * E_D;        // 8.4M
    const size_t need  = 2 * elems * sizeof(_Float16);   // ~34 MB (Kh + Vt)

    if (ws_size >= need) {
        _Float16* Kh = (_Float16*)d_ws;
        _Float16* Vt = Kh + elems;
        hipLaunchKernelGGL(cvt_kv, dim3(4096 + N_B * N_H * (L_K / 64)), dim3(256), 0, stream,
                           K, V, Kh, Vt);
        hipLaunchKernelGGL(mha_main, dim3(N_B * N_H * NQT), dim3(NT), 0, stream,
                           Q, Kh, Vt, caus, Y, W);
    } else {
        hipLaunchKernelGGL(mha_fwd_fallback, dim3(N_B * N_H * 32), dim3(256), 0, stream,
                           Q, K, V, caus, Y, W);
    }
}

// Round 15
// 266.382 us; speedup vs baseline: 1.0172x; 1.0172x over previous
//
#include <hip/hip_runtime.h>
#include <math.h>
#include <stdint.h>

// Problem constants
#define N_B 4
#define N_H 16
#define L_Q 2048
#define L_K 2048
#define E_D 1024
#define DH  64
#define QB  128          // main kernel q-rows per block (8 waves x 16 rows)
#define KB  64
#define NT  512
#define NQT (L_Q / QB)   // 16
#define NKT (L_K / KB)   // 32
#define LDP  72          // padded stride (f16) for Ps
#define TILE 4096        // one 64x64 f16 tile in LDS (8 KB)

typedef _Float16 f16x2 __attribute__((ext_vector_type(2)));
typedef _Float16 f16x4 __attribute__((ext_vector_type(4)));
typedef _Float16 f16x8 __attribute__((ext_vector_type(8)));
typedef float    f32x4 __attribute__((ext_vector_type(4)));

__device__ __forceinline__ f16x4 pk4(float a, float b, float c, float d) {
    f16x2 lo = __builtin_bit_cast(f16x2, __builtin_amdgcn_cvt_pkrtz(a, b));
    f16x2 hi = __builtin_bit_cast(f16x2, __builtin_amdgcn_cvt_pkrtz(c, d));
    f16x4 r; r[0] = lo[0]; r[1] = lo[1]; r[2] = hi[0]; r[3] = hi[1];
    return r;
}

__device__ __forceinline__ f16x8 pk8(float4 a, float4 b) {
    f16x4 lo = pk4(a.x, a.y, a.z, a.w);
    f16x4 hi = pk4(b.x, b.y, b.z, b.w);
    return __builtin_shufflevector(lo, hi, 0, 1, 2, 3, 4, 5, 6, 7);
}

__device__ __forceinline__ void gload16(const _Float16* g, _Float16* l) {
    __builtin_amdgcn_global_load_lds(
        (const __attribute__((address_space(1))) void*)g,
        (__attribute__((address_space(3))) void*)l, 16, 0, 0);
}

// ======================= fused prep kernel (K convert + V transpose) =========
__global__ __launch_bounds__(256)
void cvt_kv(const float* __restrict__ K, const float* __restrict__ V,
            _Float16* __restrict__ Kh, _Float16* __restrict__ Vt)
{
    __shared__ _Float16 T[64][72];
    const int b = blockIdx.x;
    const int t = threadIdx.x;
    if (b < 4096) {                       // ---- K: f32 -> f16 copy-convert ----
        size_t i = ((size_t)b * 256 + t) * 8;
        float4 c = *(const float4*)(K + i);
        float4 d = *(const float4*)(K + i + 4);
        *(f16x4*)(Kh + i)     = pk4(c.x, c.y, c.z, c.w);
        *(f16x4*)(Kh + i + 4) = pk4(d.x, d.y, d.z, d.w);
        return;
    }
    // ---- V: f32 -> f16 transpose per (n,h) 64x64 tile ----
    const int bid = b - 4096;
    const int st  = bid & 31;
    const int nh  = bid >> 5;
    const int n   = nh >> 4;
    const int h   = nh & 15;
    const float* Vb = V + ((size_t)(n * L_K + st * 64)) * E_D + h * DH;
    #pragma unroll
    for (int i = 0; i < 4; ++i) {
        int lin = t + i * 256;
        int s = lin >> 4, d = (lin & 15) * 4;
        float4 v = *(const float4*)(Vb + (size_t)s * E_D + d);
        T[d + 0][s] = (_Float16)v.x; T[d + 1][s] = (_Float16)v.y;
        T[d + 2][s] = (_Float16)v.z; T[d + 3][s] = (_Float16)v.w;
    }
    __syncthreads();
    _Float16* Ob = Vt + ((size_t)nh * DH) * L_K + st * 64;
    #pragma unroll
    for (int j = 0; j < 2; ++j) {
        int lin = t + j * 256;
        int d = lin >> 3, sc = (lin & 7) * 8;
        *(f16x8*)(Ob + (size_t)d * L_K + sc) = *(const f16x8*)&T[d][sc];
    }
}

// ======================= main kernel (round-13 configuration) =======================
// Pass A: 3-slot pair-ring, counted vmcnt(2).  Pass B: counted vmcnt(4),
// coalesced nt stores.  Longest-first qt order.
__global__ __launch_bounds__(NT)
void mha_main(const float* __restrict__ Qg, const _Float16* __restrict__ Kh,
              const _Float16* __restrict__ Vth, const int* __restrict__ causp,
              float* __restrict__ Yg, float* __restrict__ Wg)
{
    // flat LDS arena: pass A = 6 tiles (3 pair-slots); pass B = 4 tiles + Ps
    __shared__ __attribute__((aligned(16))) _Float16 SM[25600];   // 51.2 KB
    __shared__ float linv[QB];

    const int tid  = threadIdx.x;
    const int lane = tid & 63;
    const int wid  = tid >> 6;            // 0..7, band of 16 q-rows
    const int bid0 = blockIdx.x;
    const int bid  = ((bid0 & 7) << 7) + (bid0 >> 3);   // XCD swizzle (1024 % 8 == 0)
    const int qt   = (NQT - 1) - (bid & (NQT - 1));     // longest-first
    const int nh   = bid >> 4;
    const int q0   = qt * QB;
    const int n    = nh >> 4;
    const int h    = nh & 15;
    const bool causal = (*causp) != 0;
    const float scale = 0.125f;

    const int lrow = lane & 15;           // q within 16 (C/D col, B-frag col)
    const int g    = lane >> 4;
    const int rb   = wid * 16;            // wave's q-band within block
    const int rsub = g * 4;
    const int kt_end = causal ? (2 * qt + 2) : NKT;   // always even

    float*  Ybase = Yg + ((size_t)(n * L_Q + q0)) * E_D + h * DH;
    float*  Wbase = Wg + ((size_t)nh * L_Q + q0) * L_K;

    // ---- staging source addresses (inverse-swizzled per-lane; rule #21) ----
    const int srow = wid * 8 + (lane >> 3);               // tile row (64 rows, 8 waves)
    const int scol = (((lane & 7) ^ ((lane >> 3) & 7)) << 3);
    const _Float16* Ksrc0 = Kh  + ((size_t)(n * L_K) + srow) * E_D + h * DH + scol;
    const _Float16* Vsrc0 = Vth + ((size_t)nh * DH + srow) * L_K + scol;

    // ---- swizzled fragment read offsets ----
    const int swz = (lrow & 7) << 4;                      // bytes
    const int cb0 = ((g * 16) ^ swz) >> 1;                // elements
    const int cb1 = ((64 + g * 16) ^ swz) >> 1;

    // ---- Q fragments: f32 global -> f16 regs (same pk4 numerics as prep) ----
    const float* Qrowf = Qg + ((size_t)(n * L_Q + q0 + rb + lrow)) * E_D + h * DH;
    const f16x8 qf0 = pk8(*(const float4*)(Qrowf + g * 8),
                          *(const float4*)(Qrowf + g * 8 + 4));
    const f16x8 qf1 = pk8(*(const float4*)(Qrowf + 32 + g * 8),
                          *(const float4*)(Qrowf + 32 + g * 8 + 4));

    #define KSL(b)    (SM + (b) * TILE)
    #define VSL(b)    (SM + (2 + (b)) * TILE)
    #define PS_ROW(r) (SM + 4 * TILE + (size_t)(r) * LDP)
    #define FRAG(buf, tc, half) (*(const f16x8*)&(buf)[(size_t)((tc) * 16 + lrow) * 64 + ((half) ? cb1 : cb0)])

    // ============ PASS A: row sums (m == 0), 3-slot pair-ring ============
    float l_part = 0.0f;
    {
        const int np = kt_end >> 1;
        gload16(Ksrc0 + (size_t)0 * KB * E_D, SM + 0 * 8192 + wid * 512);
        gload16(Ksrc0 + (size_t)1 * KB * E_D, SM + 0 * 8192 + TILE + wid * 512);
        if (np > 1) {
            gload16(Ksrc0 + (size_t)2 * KB * E_D, SM + 1 * 8192 + wid * 512);
            gload16(Ksrc0 + (size_t)3 * KB * E_D, SM + 1 * 8192 + TILE + wid * 512);
        }
        int slot = 0;
        for (int p = 0; p < np; ++p) {
            __builtin_amdgcn_sched_barrier(0);
            if (p + 1 < np) {
                asm volatile("s_waitcnt vmcnt(2) lgkmcnt(0)" ::: "memory");
            } else {
                asm volatile("s_waitcnt vmcnt(0) lgkmcnt(0)" ::: "memory");
            }
            __builtin_amdgcn_s_barrier();
            __builtin_amdgcn_sched_barrier(0);
            if (p + 2 < np) {
                int ns = slot + 2; if (ns >= 3) ns -= 3;
                gload16(Ksrc0 + (size_t)(2 * p + 4) * KB * E_D, SM + ns * 8192 + wid * 512);
                gload16(Ksrc0 + (size_t)(2 * p + 5) * KB * E_D, SM + ns * 8192 + TILE + wid * 512);
            }
            __builtin_amdgcn_sched_barrier(0);
            const _Float16* base = SM + slot * 8192;
            #pragma unroll
            for (int half = 0; half < 2; ++half) {
                const int kt = 2 * p + half;
                const _Float16* Kc = base + half * TILE;
                f32x4 acc[4] = {};
                #pragma unroll
                for (int tc = 0; tc < 4; ++tc) {
                    acc[tc] = __builtin_amdgcn_mfma_f32_16x16x32_f16(FRAG(Kc, tc, 0), qf0, acc[tc], 0, 0, 0);
                    acc[tc] = __builtin_amdgcn_mfma_f32_16x16x32_f16(FRAG(Kc, tc, 1), qf1, acc[tc], 0, 0, 0);
                }
                const bool dm = causal && (kt >= 2 * qt);
                const int krel = (kt - 2 * qt) * 64;
                #pragma unroll
                for (int tc = 0; tc < 4; ++tc) {
                    #pragma unroll
                    for (int i = 0; i < 4; ++i) {
                        float v = acc[tc][i] * scale;
                        bool ok = !dm || (krel + tc * 16 + rsub + i <= rb + lrow);
                        l_part += ok ? __expf(v) : 0.0f;
                    }
                }
            }
            slot = slot + 1; if (slot >= 3) slot = 0;
        }
        __syncthreads();   // all ring reads done before pass-B staging / Ps writes
    }
    l_part += __shfl_xor(l_part, 16);
    l_part += __shfl_xor(l_part, 32);
    const float inv_l = 1.0f / l_part;
    linv[rb + lrow] = inv_l;   // 4 lanes write same value: benign

    // ================= PASS B: W write + O^T = V^T P^T =================
    f32x4 o[4] = {};
    gload16(Ksrc0, KSL(0) + wid * 512);
    gload16(Vsrc0, VSL(0) + wid * 512);
    __syncthreads();           // buffers full; also publishes linv

    float winv[4];
    #pragma unroll
    for (int j = 0; j < 4; ++j) winv[j] = linv[rb + (lane >> 4) + 4 * j];

    for (int kt = 0; kt < kt_end; ++kt) {
        const int cur = kt & 1;
        if (kt + 1 < kt_end) {
            gload16(Ksrc0 + (size_t)(kt + 1) * KB * E_D, KSL(cur ^ 1) + wid * 512);
            gload16(Vsrc0 + (size_t)(kt + 1) * KB,       VSL(cur ^ 1) + wid * 512);
        }

        f32x4 acc[4] = {};
        #pragma unroll
        for (int tc = 0; tc < 4; ++tc) {
            acc[tc] = __builtin_amdgcn_mfma_f32_16x16x32_f16(FRAG(KSL(cur), tc, 0), qf0, acc[tc], 0, 0, 0);
            acc[tc] = __builtin_amdgcn_mfma_f32_16x16x32_f16(FRAG(KSL(cur), tc, 1), qf1, acc[tc], 0, 0, 0);
        }

        const bool dm = causal && (kt >= 2 * qt);
        const int krel = (kt - 2 * qt) * 64;
        #pragma unroll
        for (int tc = 0; tc < 4; ++tc) {
            float v, p0, p1, p2, p3;
            v = acc[tc][0] * scale;
            p0 = (!dm || (krel + tc * 16 + rsub + 0 <= rb + lrow)) ? __expf(v) : 0.0f;
            v = acc[tc][1] * scale;
            p1 = (!dm || (krel + tc * 16 + rsub + 1 <= rb + lrow)) ? __expf(v) : 0.0f;
            v = acc[tc][2] * scale;
            p2 = (!dm || (krel + tc * 16 + rsub + 2 <= rb + lrow)) ? __expf(v) : 0.0f;
            v = acc[tc][3] * scale;
            p3 = (!dm || (krel + tc * 16 + rsub + 3 <= rb + lrow)) ? __expf(v) : 0.0f;
            *(f16x4*)(PS_ROW(rb + lrow) + tc * 16 + rsub) = pk4(p0, p1, p2, p3);
        }
        // Ps rows rb..rb+15 written & read by this wave only: lgkmcnt orders it.

        f16x8 pf0 = *(const f16x8*)(PS_ROW(rb + lrow) + g * 8);
        f16x8 pf1 = *(const f16x8*)(PS_ROW(rb + lrow) + 32 + g * 8);
        #pragma unroll
        for (int tc = 0; tc < 4; ++tc) {
            o[tc] = __builtin_amdgcn_mfma_f32_16x16x32_f16(FRAG(VSL(cur), tc, 0), pf0, o[tc], 0, 0, 0);
            o[tc] = __builtin_amdgcn_mfma_f32_16x16x32_f16(FRAG(VSL(cur), tc, 1), pf1, o[tc], 0, 0, 0);
        }

        // ---- coalesced W store: lanes 0-15 cover one full row (256 B) ----
        {
            float* Wt = Wbase + (size_t)kt * KB;
            const int c0 = (lane & 15) * 4;
            #pragma unroll
            for (int j = 0; j < 4; ++j) {
                const int rl = rb + (lane >> 4) + 4 * j;   // this wave's rows
                f16x4 pv = *(const f16x4*)(PS_ROW(rl) + c0);
                const float s = winv[j];
                f32x4 wv = { (float)pv[0] * s, (float)pv[1] * s,
                             (float)pv[2] * s, (float)pv[3] * s };
                __builtin_nontemporal_store(wv, (f32x4*)(Wt + (size_t)rl * L_K + c0));
            }
        }

        // counted-vmcnt barrier (T4): drain the 2 prefetch loads (and older
        // stores); this iteration's 4 W-stores stay in flight.
        __builtin_amdgcn_sched_barrier(0);
        asm volatile("s_waitcnt vmcnt(4) lgkmcnt(0)" ::: "memory");
        __builtin_amdgcn_s_barrier();
        __builtin_amdgcn_sched_barrier(0);
    }

    // ---- Y write ----
    #pragma unroll
    for (int tc = 0; tc < 4; ++tc) {
        f32x4 yv = { o[tc][0] * inv_l, o[tc][1] * inv_l,
                     o[tc][2] * inv_l, o[tc][3] * inv_l };
        __builtin_nontemporal_store(yv, (f32x4*)(Ybase + (size_t)(rb + lrow) * E_D + tc * 16 + rsub));
    }

    // ---- zero-fill masked upper columns ----
    if (causal && kt_end < NKT) {
        const int c0 = kt_end * KB;
        const int rem4 = (L_K - c0) >> 2;
        const f32x4 z = { 0.f, 0.f, 0.f, 0.f };
        for (int r = 0; r < QB; ++r) {
            float* row = Wbase + (size_t)r * L_K + c0;
            for (int c4 = tid; c4 < rem4; c4 += NT) {
                __builtin_nontemporal_store(z, (f32x4*)(row + c4 * 4));
            }
        }
    }
    #undef KSL
    #undef VSL
    #undef PS_ROW
    #undef FRAG
}

// ======================= fallback (round-3 proven kernel) =======================
__global__ __launch_bounds__(256)
void mha_fwd_fallback(const float* __restrict__ Qg, const float* __restrict__ Kg,
                      const float* __restrict__ Vg, const int* __restrict__ causp,
                      float* __restrict__ Yg, float* __restrict__ Wg)
{
    __shared__ __attribute__((aligned(16))) _Float16 Qs[64][LDP];
    __shared__ __attribute__((aligned(16))) _Float16 Ks[64][LDP];
    __shared__ __attribute__((aligned(16))) _Float16 Psf[64][LDP];
    __shared__ __attribute__((aligned(16))) _Float16 Vt[DH][68];

    const int tid  = threadIdx.x;
    const int lane = tid & 63;
    const int wid  = tid >> 6;
    const int bid  = blockIdx.x;
    const int qt   = bid & 31;
    const int nh   = bid >> 5;
    const int q0   = qt * 64;
    const int n    = nh >> 4;
    const int h    = nh & 15;
    const bool causal = (*causp) != 0;
    const float scale = 0.125f;

    const float* Qbase = Qg + ((size_t)(n * L_Q + q0)) * E_D + h * DH;
    const float* Kbase = Kg + ((size_t)n * L_K) * E_D + h * DH;
    const float* Vbase = Vg + ((size_t)n * L_K) * E_D + h * DH;
    float*       Ybase = Yg + ((size_t)(n * L_Q + q0)) * E_D + h * DH;
    float*       Wbase = Wg + ((size_t)nh * L_Q + q0) * L_K;

    const int lrow = lane & 15;
    const int lk   = (lane >> 4) * 8;
    const int rb   = wid * 16;
    const int rsub = (lane >> 4) * 4;
    const int kt_end = causal ? (qt + 1) : NKT;

    #pragma unroll
    for (int i = 0; i < 4; ++i) {
        int lin = tid + i * 256;
        int r = lin >> 4;
        int c = (lin & 15) * 4;
        float4 qv = *(const float4*)(Qbase + (size_t)r * E_D + c);
        *(f16x4*)&Qs[r][c] = pk4(qv.x, qv.y, qv.z, qv.w);
    }
    __syncthreads();
    const f16x8 qf0 = *(const f16x8*)&Qs[rb + lrow][lk];
    const f16x8 qf1 = *(const f16x8*)&Qs[rb + lrow][32 + lk];

    float l_part = 0.0f;
    for (int kt = 0; kt < kt_end; ++kt) {
        const float* Kt = Kbase + (size_t)kt * KB * E_D;
        __syncthreads();
        #pragma unroll
        for (int i = 0; i < 4; ++i) {
            int lin = tid + i * 256;
            int r = lin >> 4;
            int c = (lin & 15) * 4;
            float4 kv = *(const float4*)(Kt + (size_t)r * E_D + c);
            *(f16x4*)&Ks[r][c] = pk4(kv.x, kv.y, kv.z, kv.w);
        }
        __syncthreads();
        f32x4 acc[4] = {};
        #pragma unroll
        for (int tc = 0; tc < 4; ++tc) {
            f16x8 a0 = *(const f16x8*)&Ks[tc * 16 + lrow][lk];
            f16x8 a1 = *(const f16x8*)&Ks[tc * 16 + lrow][32 + lk];
            acc[tc] = __builtin_amdgcn_mfma_f32_16x16x32_f16(a0, qf0, acc[tc], 0, 0, 0);
            acc[tc] = __builtin_amdgcn_mfma_f32_16x16x32_f16(a1, qf1, acc[tc], 0, 0, 0);
        }
        const bool dm = causal && (kt == qt);
        #pragma unroll
        for (int tc = 0; tc < 4; ++tc) {
            #pragma unroll
            for (int i = 0; i < 4; ++i) {
                float v = acc[tc][i] * scale;
                bool ok = !dm || (tc * 16 + rsub + i <= rb + lrow);
                l_part += ok ? __expf(v) : 0.0f;
            }
        }
    }
    l_part += __shfl_xor(l_part, 16);
    l_part += __shfl_xor(l_part, 32);
    const float inv_l = 1.0f / l_part;

    f32x4 o[4] = {};
    for (int kt = 0; kt < kt_end; ++kt) {
        const float* Kt  = Kbase + (size_t)kt * KB * E_D;
        const float* Vtg = Vbase + (size_t)kt * KB * E_D;
        __syncthreads();
        #pragma unroll
        for (int i = 0; i < 4; ++i) {
            int lin = tid + i * 256;
            int r = lin >> 4;
            int c = (lin & 15) * 4;
            float4 kv = *(const float4*)(Kt + (size_t)r * E_D + c);
            *(f16x4*)&Ks[r][c] = pk4(kv.x, kv.y, kv.z, kv.w);
            int d   = lin & 63;
            int kk0 = (lin >> 6) * 4;
            float v0 = Vtg[(size_t)(kk0 + 0) * E_D + d];
            float v1 = Vtg[(size_t)(kk0 + 1) * E_D + d];
            float v2 = Vtg[(size_t)(kk0 + 2) * E_D + d];
            float v3 = Vtg[(size_t)(kk0 + 3) * E_D + d];
            *(f16x4*)&Vt[d][kk0] = pk4(v0, v1, v2, v3);
        }
        __syncthreads();
        f32x4 acc[4] = {};
        #pragma unroll
        for (int tc = 0; tc < 4; ++tc) {
            f16x8 a0 = *(const f16x8*)&Ks[tc * 16 + lrow][lk];
            f16x8 a1 = *(const f16x8*)&Ks[tc * 16 + lrow][32 + lk];
            acc[tc] = __builtin_amdgcn_mfma_f32_16x16x32_f16(a0, qf0, acc[tc], 0, 0, 0);
            acc[tc] = __builtin_amdgcn_mfma_f32_16x16x32_f16(a1, qf1, acc[tc], 0, 0, 0);
        }
        const bool dm = causal && (kt == qt);
        float* Wrow = Wbase + (size_t)(rb + lrow) * L_K + kt * KB;
        #pragma unroll
        for (int tc = 0; tc < 4; ++tc) {
            float v, p0, p1, p2, p3;
            v = acc[tc][0] * scale;
            p0 = (!dm || (tc * 16 + rsub + 0 <= rb + lrow)) ? __expf(v) : 0.0f;
            v = acc[tc][1] * scale;
            p1 = (!dm || (tc * 16 + rsub + 1 <= rb + lrow)) ? __expf(v) : 0.0f;
            v = acc[tc][2] * scale;
            p2 = (!dm || (tc * 16 + rsub + 2 <= rb + lrow)) ? __expf(v) : 0.0f;
            v = acc[tc][3] * scale;
            p3 = (!dm || (tc * 16 + rsub + 3 <= rb + lrow)) ? __expf(v) : 0.0f;
            float4 wv = make_float4(p0 * inv_l, p1 * inv_l, p2 * inv_l, p3 * inv_l);
            *(float4*)(Wrow + tc * 16 + rsub) = wv;
            *(f16x4*)&Psf[rb + lrow][tc * 16 + rsub] = pk4(p0, p1, p2, p3);
        }
        f16x8 pf0 = *(const f16x8*)&Psf[rb + lrow][lk];
        f16x8 pf1 = *(const f16x8*)&Psf[rb + lrow][32 + lk];
        #pragma unroll
        for (int tc = 0; tc < 4; ++tc) {
            f16x4 t0 = *(const f16x4*)&Vt[tc * 16 + lrow][lk];
            f16x4 t1 = *(const f16x4*)&Vt[tc * 16 + lrow][lk + 4];
            f16x8 a0 = __builtin_shufflevector(t0, t1, 0, 1, 2, 3, 4, 5, 6, 7);
            f16x4 t2 = *(const f16x4*)&Vt[tc * 16 + lrow][32 + lk];
            f16x4 t3 = *(const f16x4*)&Vt[tc * 16 + lrow][32 + lk + 4];
            f16x8 a1 = __builtin_shufflevector(t2, t3, 0, 1, 2, 3, 4, 5, 6, 7);
            o[tc] = __builtin_amdgcn_mfma_f32_16x16x32_f16(a0, pf0, o[tc], 0, 0, 0);
            o[tc] = __builtin_amdgcn_mfma_f32_16x16x32_f16(a1, pf1, o[tc], 0, 0, 0);
        }
    }
    #pragma unroll
    for (int tc = 0; tc < 4; ++tc) {
        float4 yv = make_float4(o[tc][0] * inv_l, o[tc][1] * inv_l,
                                o[tc][2] * inv_l, o[tc][3] * inv_l);
        *(float4*)(Ybase + (size_t)(rb + lrow) * E_D + tc * 16 + rsub) = yv;
    }
    if (causal && kt_end < NKT) {
        const int c0 = kt_end * KB;
        const int rem4 = (L_K - c0) >> 2;
        const float4 z = make_float4(0.f, 0.f, 0.f, 0.f);
        for (int r = 0; r < 64; ++r) {
            float* row = Wbase + (size_t)r * L_K + c0;
            for (int c4 = tid; c4 < rem4; c4 += 256) {
                *(float4*)(row + c4 * 4) = z;
            }
        }
    }
}

extern "C" void kernel_launch(void* const* d_in, const int* in_sizes, int n_in,
                              void* d_out, int out_size, void* d_ws, size_t ws_size,
                              hipStream_t stream) {
    const float* Q  = (const float*)d_in[0];
    const float* K  = (const float*)d_in[1];
    const float* V  = (const float*)d_in[2];
    const int* caus = (const int*)d_in[3];
    float* Y = (float*)d_out;
    float* W = (float*)d_out + (size_t)N_B * L_Q * E_D;

    const size_t elems = (size_t)N_B * L_Q * E_D;        // 8.4M
    const size_t need  = 2 * elems * sizeof(_Float16);   // ~34 MB (Kh + Vt)

    if (ws_size >= need) {
        _Float16* Kh = (_Float16*)d_ws;
        _Float16* Vt = Kh + elems;
        hipLaunchKernelGGL(cvt_kv, dim3(4096 + N_B * N_H * (L_K / 64)), dim3(256), 0, stream,
                           K, V, Kh, Vt);
        hipLaunchKernelGGL(mha_main, dim3(N_B * N_H * NQT), dim3(NT), 0, stream,
                           Q, Kh, Vt, caus, Y, W);
    } else {
        hipLaunchKernelGGL(mha_fwd_fallback, dim3(N_B * N_H * 32), dim3(256), 0, stream,
                           Q, K, V, caus, Y, W);
    }
}